// Round 11
// baseline (315.207 us; speedup 1.0000x reference)
//
#include <hip/hip_runtime.h>
#include <math.h>

#define B_ 32
#define N_ 1024
#define F_ 64
#define P_ 8
#define n_ 128
#define m_ 256
#define e_ 1024
#define EF_ 8
#define T_ 16
#define H_ 128
#define W_ 8
#define G_ 128
#define R_ 256
#define L2_ 128

typedef unsigned short u16;
typedef unsigned int u32;
typedef __attribute__((ext_vector_type(8))) short bf16x8;
typedef __attribute__((ext_vector_type(4))) float f32x4;

__device__ __forceinline__ float leakyf(float z, float s) { return z >= 0.f ? z : s * z; }

__device__ __forceinline__ u16 f2bf(float f) {
    u32 u = __float_as_uint(f);
    u += 0x7FFFu + ((u >> 16) & 1u);
    return (u16)(u >> 16);
}
__device__ __forceinline__ float bf2f(u16 h) { return __uint_as_float(((u32)h) << 16); }
__device__ __forceinline__ u32 pk(float a, float b) { return (u32)f2bf(a) | ((u32)f2bf(b) << 16); }

// ---- f32 LDS helpers ----
__device__ __forceinline__ int swz64(int r, int c) {
    return r * 64 + ((((c >> 2) ^ ((r >> 3) & 15)) << 2) | (c & 3));
}
__device__ __forceinline__ float4 ld64(const float* lds, int r, int c4) {
    return *reinterpret_cast<const float4*>(lds + r * 64 + ((c4 ^ ((r >> 3) & 15)) << 2));
}

// ---- bf16 LDS tiles: [rows][64]/[rows][128]/[rows][512], chunk-of-8 XOR swizzle ----
__device__ __forceinline__ int swzi(int row, int col) {
    return row * 64 + ((((col >> 3) ^ (row & 7)) << 3) | (col & 7));
}
__device__ __forceinline__ bf16x8 ldfrag(const u16* lds, int row, int kb) {
    return *reinterpret_cast<const bf16x8*>(lds + row * 64 + ((((kb >> 3) ^ (row & 7)) << 3)));
}
__device__ __forceinline__ int swzi128(int row, int col) {
    return row * 128 + ((((col >> 3) ^ (row & 7)) << 3) | (col & 7));
}
__device__ __forceinline__ bf16x8 ldfrag128(const u16* lds, int row, int kb) {
    return *reinterpret_cast<const bf16x8*>(lds + row * 128 + ((((kb >> 3) ^ (row & 7)) << 3)));
}
__device__ __forceinline__ bf16x8 ldfrag512(const u16* lds, int row, int kb) {
    return *reinterpret_cast<const bf16x8*>(lds + row * 512 + ((((kb >> 3) ^ (row & 7)) << 3)));
}

// ---------------- prep: f32 -> bf16 copies of linc, rinc, gcw ----------------
__global__ __launch_bounds__(256) void k_prep(const float* __restrict__ linc,
                                              const float* __restrict__ rinc,
                                              const float* __restrict__ gcw,
                                              u16* __restrict__ lincbf,
                                              u16* __restrict__ rincbf,
                                              u16* __restrict__ gcwbf) {
    int i = blockIdx.x * 256 + threadIdx.x;
    const float* src;
    u16* dst;
    int base;
    if (i < 262144) { src = linc; dst = lincbf; base = 0; }
    else if (i < 786432) { src = rinc; dst = rincbf; base = 262144; }
    else { src = gcw; dst = gcwbf; base = 786432; }
    int j = i - base;
    float4 v = reinterpret_cast<const float4*>(src)[j];
    ushort4 o = make_ushort4(f2bf(v.x), f2bf(v.y), f2bf(v.z), f2bf(v.w));
    reinterpret_cast<ushort4*>(dst)[j] = o;
}

// ---------------- prep2: lincT, Bw(k4w|k1w|k2w|k1b|0), efbf, k5w tile ----------------
__global__ __launch_bounds__(256) void k_prep2(const float* __restrict__ linc,
                                               const float* __restrict__ k4w,
                                               const float* __restrict__ k1w,
                                               const float* __restrict__ k2w,
                                               const float* __restrict__ k1b,
                                               const float* __restrict__ ef,
                                               const float* __restrict__ k5w,
                                               u16* __restrict__ lincT,
                                               u16* __restrict__ Bw,
                                               u16* __restrict__ efb,
                                               u16* __restrict__ k5wb) {
    const int blk = blockIdx.x, t = threadIdx.x;
    if (blk < 64) {  // transpose linc[p][n][e] tile -> lincT[p][e][n]
        const int p = blk >> 3, et = blk & 7, e0 = et * 128;
        __shared__ u16 S[128 * 128];
        {
            const int nn = t >> 1, seg = (t & 1) * 64;
            const float4* src = reinterpret_cast<const float4*>(
                linc + (size_t)(p * n_ + nn) * e_ + e0 + seg);
#pragma unroll
            for (int q = 0; q < 16; q += 2) {
                float4 a = src[q], b2 = src[q + 1];
                uint4 o = make_uint4(pk(a.x, a.y), pk(a.z, a.w), pk(b2.x, b2.y), pk(b2.z, b2.w));
                int colbase = seg + q * 4;
                int ch = (colbase >> 3) ^ (nn & 7);
                *reinterpret_cast<uint4*>(S + nn * 128 + ch * 8) = o;
            }
        }
        __syncthreads();
        {
            const int e = t >> 1, ns = (t & 1) * 64;
            u16* dst = lincT + ((size_t)(p * e_) + e0 + e) * n_ + ns;
#pragma unroll
            for (int q = 0; q < 8; q++) {
                u16 v[8];
#pragma unroll
                for (int k = 0; k < 8; k++) v[k] = S[swzi128(ns + q * 8 + k, e)];
                uint4 o = make_uint4((u32)v[0] | ((u32)v[1] << 16), (u32)v[2] | ((u32)v[3] << 16),
                                     (u32)v[4] | ((u32)v[5] << 16), (u32)v[6] | ((u32)v[7] << 16));
                *reinterpret_cast<uint4*>(dst + q * 8) = o;
            }
        }
    } else if (blk < 68) {  // Bw[p][h][128] = k4w(64) | k1w(8) | k2w(16) | k1b(1) | 0(39)
        int flat = (blk - 64) * 256 + t;  // p*128+h
        int p = flat >> 7, h = flat & 127;
        u16* dst = Bw + (size_t)flat * 128;
        const float4* s4 = reinterpret_cast<const float4*>(k4w + (size_t)(p * H_ + h) * F_);
#pragma unroll
        for (int q = 0; q < 16; q += 2) {
            float4 a = s4[q], b2 = s4[q + 1];
            *reinterpret_cast<uint4*>(dst + q * 4) =
                make_uint4(pk(a.x, a.y), pk(a.z, a.w), pk(b2.x, b2.y), pk(b2.z, b2.w));
        }
        {
            const float4* s1 = reinterpret_cast<const float4*>(k1w + (size_t)(p * H_ + h) * EF_);
            float4 a = s1[0], b2 = s1[1];
            *reinterpret_cast<uint4*>(dst + 64) =
                make_uint4(pk(a.x, a.y), pk(a.z, a.w), pk(b2.x, b2.y), pk(b2.z, b2.w));
        }
        {
            const float4* s2 = reinterpret_cast<const float4*>(k2w + (size_t)(p * H_ + h) * T_);
#pragma unroll
            for (int q = 0; q < 4; q += 2) {
                float4 a = s2[q], b2 = s2[q + 1];
                *reinterpret_cast<uint4*>(dst + 72 + q * 4) =
                    make_uint4(pk(a.x, a.y), pk(a.z, a.w), pk(b2.x, b2.y), pk(b2.z, b2.w));
            }
        }
        *reinterpret_cast<uint4*>(dst + 88) = make_uint4((u32)f2bf(k1b[p * H_ + h]), 0, 0, 0);
        *reinterpret_cast<uint4*>(dst + 96) = make_uint4(0, 0, 0, 0);
        *reinterpret_cast<uint4*>(dst + 104) = make_uint4(0, 0, 0, 0);
        *reinterpret_cast<uint4*>(dst + 112) = make_uint4(0, 0, 0, 0);
        *reinterpret_cast<uint4*>(dst + 120) = make_uint4(0, 0, 0, 0);
    } else if (blk < 100) {  // efb[p][e][8] from ef[p][e][9] cols 0..8
        int flat = (blk - 68) * 256 + t;  // p*1024+e
        const float* s = ef + (size_t)flat * (EF_ + 1);
        float v0 = s[0], v1 = s[1], v2 = s[2], v3 = s[3], v4 = s[4], v5 = s[5], v6 = s[6], v7 = s[7];
        *reinterpret_cast<uint4*>(efb + (size_t)flat * 8) =
            make_uint4(pk(v0, v1), pk(v2, v3), pk(v4, v5), pk(v6, v7));
    } else {  // k5wb[p][16][128], pre-swizzled, rows 8..15 zero
        int p = blk - 100;
        int row = t >> 4, col8 = (t & 15) * 8;
        uint4 o = make_uint4(0, 0, 0, 0);
        if (row < 8) {
            const float4* s = reinterpret_cast<const float4*>(k5w + (size_t)(p * W_ + row) * H_ + col8);
            float4 a = s[0], b2 = s[1];
            o = make_uint4(pk(a.x, a.y), pk(a.z, a.w), pk(b2.x, b2.y), pk(b2.z, b2.w));
        }
        int ch = (col8 >> 3) ^ (row & 7);
        *reinterpret_cast<uint4*>(k5wb + (size_t)p * 2048 + row * 128 + ch * 8) = o;
    }
}

// ---------------- K1 (MFMA): rx[b,p,e,f] = sum_m rinc[p,e,m] * x[b,nbr[p,m],f] ----------------
__global__ __launch_bounds__(256) void k_rx(const float* __restrict__ x,
                                            const u16* __restrict__ rincbf,
                                            const int* __restrict__ nbr,
                                            u16* __restrict__ rxbf) {
    const int et = blockIdx.x, p = blockIdx.y, b = blockIdx.z;
    const int t = threadIdx.x, lane = t & 63, wid = t >> 6;
    __shared__ __align__(16) u16 A_lds[128 * 64];
    __shared__ __align__(16) u16 BT_lds[64 * 64];
    f32x4 acc[2][4];
#pragma unroll
    for (int i = 0; i < 2; i++)
#pragma unroll
        for (int j = 0; j < 4; j++) acc[i][j] = 0.f;

    const int e0 = et * 128;
    for (int c = 0; c < 4; c++) {
        const int m0 = c * 64;
        __syncthreads();
        {
            int ee = t >> 1, seg = t & 1;
            const uint4* src = reinterpret_cast<const uint4*>(
                rincbf + ((size_t)(p * e_ + e0 + ee) * m_ + m0 + seg * 32));
#pragma unroll
            for (int q = 0; q < 4; q++) {
                uint4 v = src[q];
                int ch = (seg * 4 + q) ^ (ee & 7);
                *reinterpret_cast<uint4*>(A_lds + ee * 64 + ch * 8) = v;
            }
        }
        {
            int mm = t >> 2, fq = (t & 3) * 16;
            int row = nbr[p * m_ + m0 + mm];
            const float4* sx = reinterpret_cast<const float4*>(
                x + (size_t)(b * N_ + row) * F_ + fq);
#pragma unroll
            for (int q = 0; q < 4; q++) {
                float4 v = sx[q];
                int f0 = fq + q * 4;
                BT_lds[swzi(f0 + 0, mm)] = f2bf(v.x);
                BT_lds[swzi(f0 + 1, mm)] = f2bf(v.y);
                BT_lds[swzi(f0 + 2, mm)] = f2bf(v.z);
                BT_lds[swzi(f0 + 3, mm)] = f2bf(v.w);
            }
        }
        __syncthreads();
        const int wm0 = wid * 32, r15 = lane & 15, g4 = lane >> 4;
#pragma unroll
        for (int ks = 0; ks < 2; ks++) {
            int kb = ks * 32 + g4 * 8;
            bf16x8 af[2], bfr[4];
#pragma unroll
            for (int mf = 0; mf < 2; mf++) af[mf] = ldfrag(A_lds, wm0 + mf * 16 + r15, kb);
#pragma unroll
            for (int nf = 0; nf < 4; nf++) bfr[nf] = ldfrag(BT_lds, nf * 16 + r15, kb);
#pragma unroll
            for (int mf = 0; mf < 2; mf++)
#pragma unroll
                for (int nf = 0; nf < 4; nf++)
                    acc[mf][nf] = __builtin_amdgcn_mfma_f32_16x16x32_bf16(af[mf], bfr[nf], acc[mf][nf], 0, 0, 0);
        }
    }
    const int r15 = lane & 15, g4 = lane >> 4;
#pragma unroll
    for (int mf = 0; mf < 2; mf++)
#pragma unroll
        for (int nf = 0; nf < 4; nf++)
#pragma unroll
            for (int r = 0; r < 4; r++) {
                int erow = e0 + wid * 32 + mf * 16 + g4 * 4 + r;
                int f = nf * 16 + r15;
                rxbf[((size_t)(b * P_ + p) * e_ + erow) * F_ + f] = f2bf(acc[mf][nf][r]);
            }
}

// ---------------- K2: uT[b,p,h,n] (bf16) = sum_f k3_w[p,h,f] * x[b,nodes[p,n],f] ----------------
__global__ __launch_bounds__(256) void k_u(const float* __restrict__ x,
                                           const float* __restrict__ k3w,
                                           const int* __restrict__ nodes,
                                           u16* __restrict__ uT) {
    const int p = blockIdx.x, b = blockIdx.y;
    const int t = threadIdx.x;
    const int th = t & 15;
    const int tn = t >> 4;
    __shared__ float xg[128 * 64];
    __shared__ float kw[128 * 64];
    for (int idx = t; idx < 8192; idx += 256) {
        int r = idx >> 6, f = idx & 63;
        int row = nodes[p * n_ + r];
        xg[swz64(r, f)] = x[(size_t)(b * N_ + row) * F_ + f];
        kw[swz64(r, f)] = k3w[(size_t)(p * H_ + r) * F_ + f];
    }
    __syncthreads();
    float acc[8][8];
#pragma unroll
    for (int i = 0; i < 8; i++)
#pragma unroll
        for (int j = 0; j < 8; j++) acc[i][j] = 0.f;
#pragma unroll 2
    for (int k4 = 0; k4 < 16; k4++) {
        float4 xv[8];
#pragma unroll
        for (int i = 0; i < 8; i++) xv[i] = ld64(xg, tn * 8 + i, k4);
#pragma unroll
        for (int j = 0; j < 8; j++) {
            float4 kv = ld64(kw, th * 8 + j, k4);
#pragma unroll
            for (int i = 0; i < 8; i++) {
                acc[i][j] += xv[i].x * kv.x + xv[i].y * kv.y + xv[i].z * kv.z + xv[i].w * kv.w;
            }
        }
    }
    // write transposed bf16: uT[h][n]
#pragma unroll
    for (int j = 0; j < 8; j++) {
        uint4 o = make_uint4(pk(acc[0][j], acc[1][j]), pk(acc[2][j], acc[3][j]),
                             pk(acc[4][j], acc[5][j]), pk(acc[6][j], acc[7][j]));
        *reinterpret_cast<uint4*>(uT + ((size_t)(b * P_ + p) * H_ + th * 8 + j) * n_ + tn * 8) = o;
    }
}

// ---------------- K3 (MFMA): kernel[b,p,e,w] ----------------
__global__ __launch_bounds__(256) void k_kern(const u16* __restrict__ lincT,
                                              const u16* __restrict__ uT,
                                              const u16* __restrict__ rxbf,
                                              const u16* __restrict__ Bw,
                                              const u16* __restrict__ efb,
                                              const float* __restrict__ tin,
                                              const u16* __restrict__ k5wb,
                                              const float* __restrict__ k5b,
                                              float* __restrict__ kern) {
    const int et = blockIdx.x, p = blockIdx.y, b = blockIdx.z;
    const int t = threadIdx.x, lane = t & 63, wid = t >> 6;
    const int r15 = lane & 15, g4 = lane >> 4;
    const int wm = (wid >> 1) * 64, wn = (wid & 1) * 64;
    __shared__ __align__(16) u16 S[128 * 128 + 16 * 128];
    u16* A_lds = S;
    u16* B_lds = S + 8192;
    u16* k5l = S + 16384;

    {
        uint4 v = reinterpret_cast<const uint4*>(k5wb + (size_t)p * 2048)[t];
        reinterpret_cast<uint4*>(k5l)[t] = v;
    }
    uint4 tinlo, tinhi;
    {
        const float4* s = reinterpret_cast<const float4*>(tin + b * T_);
        float4 a = s[0], b2 = s[1], c2 = s[2], d2 = s[3];
        tinlo = make_uint4(pk(a.x, a.y), pk(a.z, a.w), pk(b2.x, b2.y), pk(b2.z, b2.w));
        tinhi = make_uint4(pk(c2.x, c2.y), pk(c2.z, c2.w), pk(d2.x, d2.y), pk(d2.z, d2.w));
    }

    f32x4 acc[4][4];
#pragma unroll
    for (int i = 0; i < 4; i++)
#pragma unroll
        for (int j = 0; j < 4; j++) acc[i][j] = 0.f;

    const int e0 = et * 128;
    const size_t pb_e = (size_t)(b * P_ + p) * e_;
    const int row = t >> 1, half = t & 1;

    for (int c = 0; c < 4; c++) {
        __syncthreads();
        if (c < 2) {
            const uint4* src = reinterpret_cast<const uint4*>(
                lincT + ((size_t)(p * e_) + e0 + row) * n_ + c * 64 + half * 32);
#pragma unroll
            for (int q = 0; q < 4; q++) {
                uint4 v = src[q];
                int ch = (half * 4 + q) ^ (row & 7);
                *reinterpret_cast<uint4*>(A_lds + row * 64 + ch * 8) = v;
            }
        } else if (c == 2) {
            const uint4* src = reinterpret_cast<const uint4*>(
                rxbf + (pb_e + e0 + row) * F_ + half * 32);
#pragma unroll
            for (int q = 0; q < 4; q++) {
                uint4 v = src[q];
                int ch = (half * 4 + q) ^ (row & 7);
                *reinterpret_cast<uint4*>(A_lds + row * 64 + ch * 8) = v;
            }
        } else {
            uint4 w[4];
            if (half == 0) {
                w[0] = *reinterpret_cast<const uint4*>(efb + ((size_t)(p * e_) + e0 + row) * 8);
                w[1] = tinlo;
                w[2] = tinhi;
                w[3] = make_uint4(0x00003F80u, 0, 0, 0);
            } else {
                w[0] = w[1] = w[2] = w[3] = make_uint4(0, 0, 0, 0);
            }
#pragma unroll
            for (int q = 0; q < 4; q++) {
                int ch = (half * 4 + q) ^ (row & 7);
                *reinterpret_cast<uint4*>(A_lds + row * 64 + ch * 8) = w[q];
            }
        }
        {
            const uint4* src;
            if (c < 2)
                src = reinterpret_cast<const uint4*>(
                    uT + ((size_t)(b * P_ + p) * H_ + row) * n_ + c * 64 + half * 32);
            else
                src = reinterpret_cast<const uint4*>(
                    Bw + (size_t)(p * H_ + row) * 128 + (c - 2) * 64 + half * 32);
#pragma unroll
            for (int q = 0; q < 4; q++) {
                uint4 v = src[q];
                int ch = (half * 4 + q) ^ (row & 7);
                *reinterpret_cast<uint4*>(B_lds + row * 64 + ch * 8) = v;
            }
        }
        __syncthreads();
#pragma unroll
        for (int ks = 0; ks < 2; ks++) {
            int kb = ks * 32 + g4 * 8;
            bf16x8 af[4], bfr[4];
#pragma unroll
            for (int mf = 0; mf < 4; mf++) af[mf] = ldfrag(A_lds, wm + mf * 16 + r15, kb);
#pragma unroll
            for (int nf = 0; nf < 4; nf++) bfr[nf] = ldfrag(B_lds, wn + nf * 16 + r15, kb);
#pragma unroll
            for (int mf = 0; mf < 4; mf++)
#pragma unroll
                for (int nf = 0; nf < 4; nf++)
                    acc[mf][nf] = __builtin_amdgcn_mfma_f32_16x16x32_bf16(af[mf], bfr[nf], acc[mf][nf], 0, 0, 0);
        }
    }
    __syncthreads();
    u16* Kl = S;
#pragma unroll
    for (int mf = 0; mf < 4; mf++)
#pragma unroll
        for (int nf = 0; nf < 4; nf++)
#pragma unroll
            for (int r = 0; r < 4; r++) {
                int er = wm + mf * 16 + g4 * 4 + r;
                int hc = wn + nf * 16 + r15;
                Kl[swzi128(er, hc)] = f2bf(leakyf(acc[mf][nf][r], 0.02f));
            }
    __syncthreads();
    f32x4 acc2[2];
    acc2[0] = 0.f;
    acc2[1] = 0.f;
#pragma unroll
    for (int ks = 0; ks < 4; ks++) {
        int kb = ks * 32 + g4 * 8;
        bf16x8 bf5 = ldfrag128(k5l, r15, kb);
#pragma unroll
        for (int mf2 = 0; mf2 < 2; mf2++) {
            bf16x8 af = ldfrag128(Kl, wid * 32 + mf2 * 16 + r15, kb);
            acc2[mf2] = __builtin_amdgcn_mfma_f32_16x16x32_bf16(af, bf5, acc2[mf2], 0, 0, 0);
        }
    }
    if (r15 < 8) {
        float kb5 = k5b[p * W_ + r15];
#pragma unroll
        for (int mf2 = 0; mf2 < 2; mf2++)
#pragma unroll
            for (int r = 0; r < 4; r++) {
                int er = e0 + wid * 32 + mf2 * 16 + g4 * 4 + r;
                kern[(pb_e + er) * W_ + r15] = fmaxf(acc2[mf2][r] + kb5, 0.f);
            }
    }
}

// ---------------- K4 (MFMA): QT[b,p,g,e] = sum_k gcw[g,k] * B'[e,k],  B'[e,w*64+f]=kern[e,w]*rx[e,f]
// Single K=512 GEMM. B' built ONCE per block in LDS (32e x 512k); gcw streamed in
// K=64 chunks, double-buffered (1 barrier/chunk). Block 32e x 128g, grid 32x8x32.
__global__ __launch_bounds__(256) void k_q(const u16* __restrict__ rxbf,
                                           const float* __restrict__ kernb,
                                           const u16* __restrict__ gcwbf,
                                           u16* __restrict__ QTbf) {
    const int et = blockIdx.x, p = blockIdx.y, b = blockIdx.z;
    const int t = threadIdx.x, lane = t & 63, wid = t >> 6;
    const int r15 = lane & 15, g4 = lane >> 4;
    const int wn = wid * 32;
    __shared__ __align__(16) u16 BP[32 * 512];     // B'[e-local][k], per-row chunk swizzle
    __shared__ __align__(16) u16 GW[2][128 * 64];  // gcw chunk [g][k64]
    const int e0 = et * 32;
    const size_t pb_e = (size_t)(b * P_ + p) * e_;

    {   // build B' once: row = t>>3 (32 rows), w = t&7
        const int row = t >> 3, w = t & 7;
        const float ksc = kernb[(pb_e + e0 + row) * W_ + w];
        const uint4* src = reinterpret_cast<const uint4*>(rxbf + (pb_e + e0 + row) * F_);
        u16* dstrow = BP + row * 512;
#pragma unroll
        for (int q = 0; q < 8; q++) {
            uint4 v = src[q];
            u32 vv[4] = {v.x, v.y, v.z, v.w};
            u32 ov[4];
#pragma unroll
            for (int q2 = 0; q2 < 4; q2++) {
                float f0 = bf2f((u16)(vv[q2] & 0xFFFF)) * ksc;
                float f1 = bf2f((u16)(vv[q2] >> 16)) * ksc;
                ov[q2] = (u32)f2bf(f0) | ((u32)f2bf(f1) << 16);
            }
            int ch = (w * 8 + q) ^ (row & 7);
            *reinterpret_cast<uint4*>(dstrow + ch * 8) = make_uint4(ov[0], ov[1], ov[2], ov[3]);
        }
    }
    const int gg = t >> 1, seg = t & 1;
    {   // stage gcw chunk 0
        const uint4* gsrc = reinterpret_cast<const uint4*>(
            gcwbf + (size_t)(p * G_ + gg) * 512 + seg * 32);
#pragma unroll
        for (int q = 0; q < 4; q++) {
            uint4 v = gsrc[q];
            int ch = (seg * 4 + q) ^ (gg & 7);
            *reinterpret_cast<uint4*>(GW[0] + gg * 64 + ch * 8) = v;
        }
    }
    __syncthreads();

    f32x4 acc[2][2];
#pragma unroll
    for (int i = 0; i < 2; i++)
#pragma unroll
        for (int j = 0; j < 2; j++) acc[i][j] = 0.f;

    for (int c = 0; c < 8; c++) {
        const int cur = c & 1;
        if (c < 7) {  // prefetch next gcw chunk
            const uint4* gsrc = reinterpret_cast<const uint4*>(
                gcwbf + (size_t)(p * G_ + gg) * 512 + (c + 1) * 64 + seg * 32);
#pragma unroll
            for (int q = 0; q < 4; q++) {
                uint4 v = gsrc[q];
                int ch = (seg * 4 + q) ^ (gg & 7);
                *reinterpret_cast<uint4*>(GW[cur ^ 1] + gg * 64 + ch * 8) = v;
            }
        }
        bf16x8 af[2][2], bfr[2][2];
#pragma unroll
        for (int mf = 0; mf < 2; mf++)
#pragma unroll
            for (int ks = 0; ks < 2; ks++)
                af[mf][ks] = ldfrag512(BP, mf * 16 + r15, c * 64 + ks * 32 + g4 * 8);
#pragma unroll
        for (int nf = 0; nf < 2; nf++)
#pragma unroll
            for (int ks = 0; ks < 2; ks++)
                bfr[nf][ks] = ldfrag(GW[cur], wn + nf * 16 + r15, ks * 32 + g4 * 8);
#pragma unroll
        for (int mf = 0; mf < 2; mf++)
#pragma unroll
            for (int nf = 0; nf < 2; nf++)
#pragma unroll
                for (int ks = 0; ks < 2; ks++)
                    acc[mf][nf] = __builtin_amdgcn_mfma_f32_16x16x32_bf16(af[mf][ks], bfr[nf][ks], acc[mf][nf], 0, 0, 0);
        __syncthreads();
    }
    // write QT[b,p,g,e]: D row = e (A = B' rows), col = g; 4 e-contiguous per lane
#pragma unroll
    for (int mf = 0; mf < 2; mf++)
#pragma unroll
        for (int nf = 0; nf < 2; nf++) {
            int g = wn + nf * 16 + r15;
            int er = e0 + mf * 16 + g4 * 4;
            ushort4 o = make_ushort4(f2bf(acc[mf][nf][0]), f2bf(acc[mf][nf][1]),
                                     f2bf(acc[mf][nf][2]), f2bf(acc[mf][nf][3]));
            *reinterpret_cast<ushort4*>(QTbf + ((size_t)(b * P_ + p) * G_ + g) * e_ + er) = o;
        }
}

// ---------------- K5 (MFMA): y2[b,p,n,g] = relu(sum_e linc[n,e]*QT[g,e] + gcb[g]) ----------------
__global__ __launch_bounds__(256) void k_y2(const u16* __restrict__ lincbf,
                                            const u16* __restrict__ QTbf,
                                            const float* __restrict__ gcb,
                                            float* __restrict__ y2) {
    const int p = blockIdx.x, b = blockIdx.y;
    const int t = threadIdx.x, lane = t & 63, wid = t >> 6;
    __shared__ __align__(16) u16 A_lds[128 * 64];
    __shared__ __align__(16) u16 BT_lds[128 * 64];
    f32x4 acc[4][4];
#pragma unroll
    for (int i = 0; i < 4; i++)
#pragma unroll
        for (int j = 0; j < 4; j++) acc[i][j] = 0.f;

    const size_t pb_g = (size_t)(b * P_ + p) * G_;
    const int wm = (wid >> 1) * 64, wn = (wid & 1) * 64;
    const int r15 = lane & 15, g4 = lane >> 4;

    for (int c = 0; c < 16; c++) {
        const int e0 = c * 64;
        __syncthreads();
        {
            int nn = t >> 1, seg = t & 1;
            const uint4* src = reinterpret_cast<const uint4*>(
                lincbf + (size_t)(p * n_ + nn) * e_ + e0 + seg * 32);
#pragma unroll
            for (int q = 0; q < 4; q++) {
                uint4 v = src[q];
                int ch = (seg * 4 + q) ^ (nn & 7);
                *reinterpret_cast<uint4*>(A_lds + nn * 64 + ch * 8) = v;
            }
        }
        {
            int gg = t >> 1, seg = t & 1;
            const uint4* src = reinterpret_cast<const uint4*>(
                QTbf + (pb_g + gg) * e_ + e0 + seg * 32);
#pragma unroll
            for (int q = 0; q < 4; q++) {
                uint4 v = src[q];
                int ch = (seg * 4 + q) ^ (gg & 7);
                *reinterpret_cast<uint4*>(BT_lds + gg * 64 + ch * 8) = v;
            }
        }
        __syncthreads();
#pragma unroll
        for (int ks = 0; ks < 2; ks++) {
            int kb = ks * 32 + g4 * 8;
            bf16x8 af[4], bfr[4];
#pragma unroll
            for (int mf = 0; mf < 4; mf++) af[mf] = ldfrag(A_lds, wm + mf * 16 + r15, kb);
#pragma unroll
            for (int nf = 0; nf < 4; nf++) bfr[nf] = ldfrag(BT_lds, wn + nf * 16 + r15, kb);
#pragma unroll
            for (int mf = 0; mf < 4; mf++)
#pragma unroll
                for (int nf = 0; nf < 4; nf++)
                    acc[mf][nf] = __builtin_amdgcn_mfma_f32_16x16x32_bf16(af[mf], bfr[nf], acc[mf][nf], 0, 0, 0);
        }
    }
#pragma unroll
    for (int mf = 0; mf < 4; mf++)
#pragma unroll
        for (int nf = 0; nf < 4; nf++) {
            int g = wn + nf * 16 + r15;
            float gb = gcb[p * G_ + g];
#pragma unroll
            for (int r = 0; r < 4; r++) {
                int nrow = wm + mf * 16 + g4 * 4 + r;
                y2[((size_t)(b * P_ + p) * n_ + nrow) * G_ + g] = fmaxf(acc[mf][nf][r] + gb, 0.f);
            }
        }
}

// ---------------- K6 (MFMA): hpart[ks,p,b,r] = sum_{k in slice} r0_w[p,r,k]*y2flat[b,p,k] ----
__global__ __launch_bounds__(256) void k_h1(const float* __restrict__ r0w,
                                            const float* __restrict__ y2,
                                            float* __restrict__ hpart) {
    const int ks = blockIdx.x;   // 0..31 (512 k each)
    const int rt = blockIdx.y;   // 0..3  (64 rows each)
    const int p  = blockIdx.z;
    const int t = threadIdx.x, lane = t & 63, wid = t >> 6;
    const int r15 = lane & 15, g4 = lane >> 4;
    __shared__ __align__(16) u16 A_lds[64 * 128];  // [r][k] swizzled
    __shared__ __align__(16) u16 B_lds[32 * 128];  // [b][k] swizzled
    const int kc = ks * 512;
    const int row0 = rt * 64;

    f32x4 acc[2];
    acc[0] = 0.f;
    acc[1] = 0.f;

    const int sar = t >> 2, sas = t & 3;  // A: row (0..63), 32-float segment
    const int sbb = t >> 3, sbs = t & 7;  // B: b-row (0..31), 16-float segment

    for (int it = 0; it < 4; it++) {
        __syncthreads();
        {   // A: r0w rows (f32 -> bf16), 32 contiguous floats per thread
            const float4* src = reinterpret_cast<const float4*>(
                r0w + ((size_t)(p * R_) + row0 + sar) * 16384 + kc + it * 128 + sas * 32);
#pragma unroll
            for (int q = 0; q < 4; q++) {
                float4 a = src[q * 2], b2 = src[q * 2 + 1];
                uint4 o = make_uint4(pk(a.x, a.y), pk(a.z, a.w), pk(b2.x, b2.y), pk(b2.z, b2.w));
                int ch = (sas * 4 + q) ^ (sar & 7);
                *reinterpret_cast<uint4*>(A_lds + sar * 128 + ch * 8) = o;
            }
        }
        {   // B: y2 rows (f32 -> bf16), 16 contiguous floats per thread
            const float4* src = reinterpret_cast<const float4*>(
                y2 + (size_t)(sbb * P_ + p) * 16384 + kc + it * 128 + sbs * 16);
            float4 a = src[0], b2 = src[1], c2 = src[2], d2 = src[3];
            uint4 o0 = make_uint4(pk(a.x, a.y), pk(a.z, a.w), pk(b2.x, b2.y), pk(b2.z, b2.w));
            uint4 o1 = make_uint4(pk(c2.x, c2.y), pk(c2.z, c2.w), pk(d2.x, d2.y), pk(d2.z, d2.w));
            int ch0 = (sbs * 2) ^ (sbb & 7);
            int ch1 = (sbs * 2 + 1) ^ (sbb & 7);
            *reinterpret_cast<uint4*>(B_lds + sbb * 128 + ch0 * 8) = o0;
            *reinterpret_cast<uint4*>(B_lds + sbb * 128 + ch1 * 8) = o1;
        }
        __syncthreads();
#pragma unroll
        for (int ksl = 0; ksl < 4; ksl++) {
            int kb = ksl * 32 + g4 * 8;
            bf16x8 af = ldfrag128(A_lds, wid * 16 + r15, kb);
#pragma unroll
            for (int nf = 0; nf < 2; nf++) {
                bf16x8 bfr = ldfrag128(B_lds, nf * 16 + r15, kb);
                acc[nf] = __builtin_amdgcn_mfma_f32_16x16x32_bf16(af, bfr, acc[nf], 0, 0, 0);
            }
        }
    }
#pragma unroll
    for (int nf = 0; nf < 2; nf++) {
        int b = nf * 16 + r15;
        int r = row0 + wid * 16 + g4 * 4;
        float4 v = make_float4(acc[nf][0], acc[nf][1], acc[nf][2], acc[nf][3]);
        *reinterpret_cast<float4*>(hpart + (((size_t)(ks * P_ + p) * 32 + b) * 256 + r)) = v;
    }
}

// ---------------- K7: h -> leaky -> w -> res ----------------
__global__ __launch_bounds__(128) void k_wres(const float* __restrict__ hpart,
                                              const float* __restrict__ r1w,
                                              const float* __restrict__ r1b,
                                              const float* __restrict__ r2w,
                                              const float* __restrict__ cap,
                                              const float* __restrict__ tin,
                                              const float* __restrict__ r3w,
                                              const float* __restrict__ r3b,
                                              const float* __restrict__ y2,
                                              float* __restrict__ res) {
    const int p = blockIdx.x, b = blockIdx.y;
    const int t = threadIdx.x;
    __shared__ float lh[256];
    __shared__ float wl[128];
    for (int rr = t; rr < 256; rr += 128) {
        float s = 0.f;
        for (int ks = 0; ks < 32; ks++)
            s += hpart[(((size_t)(ks * P_ + p) * 32 + b) * 256) + rr];
        for (int tt = 0; tt < T_; tt++) s += r1w[(size_t)(p * R_ + rr) * T_ + tt] * tin[b * T_ + tt];
        s += r1b[p * R_ + rr];
        for (int nn = 0; nn < n_; nn++) s += r2w[(size_t)(p * R_ + rr) * n_ + nn] * cap[p * n_ + nn];
        lh[rr] = leakyf(s, 0.01f);
    }
    __syncthreads();
    {
        const int nn = t;
        float accw = r3b[p * n_ + nn];
        const float* r3p = r3w + (size_t)(p * n_ + nn) * R_;
        for (int r = 0; r < 256; r += 4) {
            float4 rv = *reinterpret_cast<const float4*>(r3p + r);
            accw += rv.x * lh[r] + rv.y * lh[r + 1] + rv.z * lh[r + 2] + rv.w * lh[r + 3];
        }
        wl[nn] = fmaxf(accw, 0.f);
    }
    __syncthreads();
    {
        const int g = t;
        float a = 0.f;
        for (int nn = 0; nn < n_; nn++) a += wl[nn] * y2[((size_t)(b * P_ + p) * n_ + nn) * G_ + g];
        res[(b * P_ + p) * G_ + g] = a;
    }
}

// ---------------- K8: out[b,l] ----------------
__global__ __launch_bounds__(128) void k_out(const float* __restrict__ convw,
                                             const float* __restrict__ convb,
                                             const float* __restrict__ res,
                                             float* __restrict__ out) {
    const int b = blockIdx.x;
    const int t = threadIdx.x;
    __shared__ float rl[1024];
    for (int idx = t; idx < 1024; idx += 128) rl[idx] = res[b * 1024 + idx];
    __syncthreads();
    float a = convb[t];
    const float* cw = convw + (size_t)t * 1024;
    for (int gp = 0; gp < 1024; gp += 4) {
        float4 v = *reinterpret_cast<const float4*>(cw + gp);
        a += v.x * rl[((gp + 0) & 7) * 128 + ((gp + 0) >> 3)];
        a += v.y * rl[((gp + 1) & 7) * 128 + ((gp + 1) >> 3)];
        a += v.z * rl[((gp + 2) & 7) * 128 + ((gp + 2) >> 3)];
        a += v.w * rl[((gp + 3) & 7) * 128 + ((gp + 3) >> 3)];
    }
    out[b * L2_ + t] = leakyf(a, 0.02f);
}

extern "C" void kernel_launch(void* const* d_in, const int* in_sizes, int n_in,
                              void* d_out, int out_size, void* d_ws, size_t ws_size,
                              hipStream_t stream) {
    const float* x    = (const float*)d_in[0];
    const float* tin  = (const float*)d_in[1];
    const float* ef   = (const float*)d_in[2];
    const float* linc = (const float*)d_in[3];
    const float* rinc = (const float*)d_in[4];
    const float* cap  = (const float*)d_in[5];
    const float* k1w  = (const float*)d_in[6];
    const float* k1b  = (const float*)d_in[7];
    const float* k2w  = (const float*)d_in[8];
    const float* k3w  = (const float*)d_in[9];
    const float* k4w  = (const float*)d_in[10];
    const float* k5w  = (const float*)d_in[11];
    const float* k5b  = (const float*)d_in[12];
    const float* gcw  = (const float*)d_in[13];
    const float* gcb  = (const float*)d_in[14];
    const float* r0w  = (const float*)d_in[15];
    const float* r1w  = (const float*)d_in[16];
    const float* r1b  = (const float*)d_in[17];
    const float* r2w  = (const float*)d_in[18];
    const float* r3w  = (const float*)d_in[19];
    const float* r3b  = (const float*)d_in[20];
    const float* convw = (const float*)d_in[21];
    const float* convb = (const float*)d_in[22];
    const int* nodes  = (const int*)d_in[23];
    const int* nbr    = (const int*)d_in[24];
    float* out = (float*)d_out;

    float* ws = (float*)d_ws;
    u16*   rxbf   = (u16*)ws;                  // [0, 8388608) f-slots
    u16*   uTbf   = (u16*)(ws + 8388608);      // [8388608, 10485760)
    float* kernb  = ws + 10485760;             // [10485760, 12582912)
    u16*   QTbf   = (u16*)(ws + 12582912);     // [12582912, 29360128)
    float* y2b    = ws + 29360128;             // [29360128, 33554432)
    u16*   lincbf = (u16*)(ws + 33554432);     // 524288 slots
    u16*   lincT  = (u16*)(ws + 34078720);     // 524288
    u16*   rincbf = (u16*)(ws + 34603008);     // 1048576
    u16*   gcwbf  = (u16*)(ws + 35651584);     // 262144
    u16*   Bwbf   = (u16*)(ws + 35913728);     // 65536
    u16*   efbf   = (u16*)(ws + 35979264);     // 32768
    u16*   k5wbf  = (u16*)(ws + 36012032);     // 8192
    float* hpart  = ws;                        // 2,097,152 floats: aliases rx region (dead after k_q)
    float* resb   = ws + 10485760;             // aliases kernb (dead after k_q)

    k_prep <<<3584, 256, 0, stream>>>(linc, rinc, gcw, lincbf, rincbf, gcwbf);
    k_prep2<<<108, 256, 0, stream>>>(linc, k4w, k1w, k2w, k1b, ef, k5w, lincT, Bwbf, efbf, k5wbf);
    k_rx  <<<dim3(8, P_, B_), 256, 0, stream>>>(x, rincbf, nbr, rxbf);
    k_u   <<<dim3(P_, B_),    256, 0, stream>>>(x, k3w, nodes, uTbf);
    k_kern<<<dim3(8, P_, B_), 256, 0, stream>>>(lincT, uTbf, rxbf, Bwbf, efbf, tin, k5wbf, k5b, kernb);
    k_q   <<<dim3(32, P_, B_), 256, 0, stream>>>(rxbf, kernb, gcwbf, QTbf);
    k_y2  <<<dim3(P_, B_),    256, 0, stream>>>(lincbf, QTbf, gcb, y2b);
    k_h1  <<<dim3(32, 4, P_), 256, 0, stream>>>(r0w, y2b, hpart);
    k_wres<<<dim3(P_, B_),    128, 0, stream>>>(hpart, r1w, r1b, r2w, cap, tin, r3w, r3b, y2b, resb);
    k_out <<<B_, 128, 0, stream>>>(convw, convb, resb, out);
}

// Round 12
// 257.896 us; speedup vs baseline: 1.2222x; 1.2222x over previous
//
#include <hip/hip_runtime.h>
#include <math.h>

#define B_ 32
#define N_ 1024
#define F_ 64
#define P_ 8
#define n_ 128
#define m_ 256
#define e_ 1024
#define EF_ 8
#define T_ 16
#define H_ 128
#define W_ 8
#define G_ 128
#define R_ 256
#define L2_ 128

typedef unsigned short u16;
typedef unsigned int u32;
typedef __attribute__((ext_vector_type(8))) short bf16x8;
typedef __attribute__((ext_vector_type(4))) float f32x4;

__device__ __forceinline__ float leakyf(float z, float s) { return z >= 0.f ? z : s * z; }

__device__ __forceinline__ u16 f2bf(float f) {
    u32 u = __float_as_uint(f);
    u += 0x7FFFu + ((u >> 16) & 1u);
    return (u16)(u >> 16);
}
__device__ __forceinline__ float bf2f(u16 h) { return __uint_as_float(((u32)h) << 16); }
__device__ __forceinline__ u32 pk(float a, float b) { return (u32)f2bf(a) | ((u32)f2bf(b) << 16); }

// ---- f32 LDS helpers ----
__device__ __forceinline__ int swz64(int r, int c) {
    return r * 64 + ((((c >> 2) ^ ((r >> 3) & 15)) << 2) | (c & 3));
}
__device__ __forceinline__ float4 ld64(const float* lds, int r, int c4) {
    return *reinterpret_cast<const float4*>(lds + r * 64 + ((c4 ^ ((r >> 3) & 15)) << 2));
}

// ---- bf16 LDS tiles: [rows][64] and [rows][128], chunk-of-8 XOR swizzle ----
__device__ __forceinline__ int swzi(int row, int col) {
    return row * 64 + ((((col >> 3) ^ (row & 7)) << 3) | (col & 7));
}
__device__ __forceinline__ bf16x8 ldfrag(const u16* lds, int row, int kb) {
    return *reinterpret_cast<const bf16x8*>(lds + row * 64 + ((((kb >> 3) ^ (row & 7)) << 3)));
}
__device__ __forceinline__ int swzi128(int row, int col) {
    return row * 128 + ((((col >> 3) ^ (row & 7)) << 3) | (col & 7));
}
__device__ __forceinline__ bf16x8 ldfrag128(const u16* lds, int row, int kb) {
    return *reinterpret_cast<const bf16x8*>(lds + row * 128 + ((((kb >> 3) ^ (row & 7)) << 3)));
}

// ---------------- prep: f32 -> bf16 copies of linc, rinc, gcw ----------------
__global__ __launch_bounds__(256) void k_prep(const float* __restrict__ linc,
                                              const float* __restrict__ rinc,
                                              const float* __restrict__ gcw,
                                              u16* __restrict__ lincbf,
                                              u16* __restrict__ rincbf,
                                              u16* __restrict__ gcwbf) {
    int i = blockIdx.x * 256 + threadIdx.x;
    const float* src;
    u16* dst;
    int base;
    if (i < 262144) { src = linc; dst = lincbf; base = 0; }
    else if (i < 786432) { src = rinc; dst = rincbf; base = 262144; }
    else { src = gcw; dst = gcwbf; base = 786432; }
    int j = i - base;
    float4 v = reinterpret_cast<const float4*>(src)[j];
    ushort4 o = make_ushort4(f2bf(v.x), f2bf(v.y), f2bf(v.z), f2bf(v.w));
    reinterpret_cast<ushort4*>(dst)[j] = o;
}

// ---------------- prep2: lincT, Bw(k4w|k1w|k2w|k1b|0), efbf, k5w tile ----------------
__global__ __launch_bounds__(256) void k_prep2(const float* __restrict__ linc,
                                               const float* __restrict__ k4w,
                                               const float* __restrict__ k1w,
                                               const float* __restrict__ k2w,
                                               const float* __restrict__ k1b,
                                               const float* __restrict__ ef,
                                               const float* __restrict__ k5w,
                                               u16* __restrict__ lincT,
                                               u16* __restrict__ Bw,
                                               u16* __restrict__ efb,
                                               u16* __restrict__ k5wb) {
    const int blk = blockIdx.x, t = threadIdx.x;
    if (blk < 64) {  // transpose linc[p][n][e] tile -> lincT[p][e][n]
        const int p = blk >> 3, et = blk & 7, e0 = et * 128;
        __shared__ u16 S[128 * 128];
        {
            const int nn = t >> 1, seg = (t & 1) * 64;
            const float4* src = reinterpret_cast<const float4*>(
                linc + (size_t)(p * n_ + nn) * e_ + e0 + seg);
#pragma unroll
            for (int q = 0; q < 16; q += 2) {
                float4 a = src[q], b2 = src[q + 1];
                uint4 o = make_uint4(pk(a.x, a.y), pk(a.z, a.w), pk(b2.x, b2.y), pk(b2.z, b2.w));
                int colbase = seg + q * 4;
                int ch = (colbase >> 3) ^ (nn & 7);
                *reinterpret_cast<uint4*>(S + nn * 128 + ch * 8) = o;
            }
        }
        __syncthreads();
        {
            const int e = t >> 1, ns = (t & 1) * 64;
            u16* dst = lincT + ((size_t)(p * e_) + e0 + e) * n_ + ns;
#pragma unroll
            for (int q = 0; q < 8; q++) {
                u16 v[8];
#pragma unroll
                for (int k = 0; k < 8; k++) v[k] = S[swzi128(ns + q * 8 + k, e)];
                uint4 o = make_uint4((u32)v[0] | ((u32)v[1] << 16), (u32)v[2] | ((u32)v[3] << 16),
                                     (u32)v[4] | ((u32)v[5] << 16), (u32)v[6] | ((u32)v[7] << 16));
                *reinterpret_cast<uint4*>(dst + q * 8) = o;
            }
        }
    } else if (blk < 68) {  // Bw[p][h][128] = k4w(64) | k1w(8) | k2w(16) | k1b(1) | 0(39)
        int flat = (blk - 64) * 256 + t;  // p*128+h
        int p = flat >> 7, h = flat & 127;
        u16* dst = Bw + (size_t)flat * 128;
        const float4* s4 = reinterpret_cast<const float4*>(k4w + (size_t)(p * H_ + h) * F_);
#pragma unroll
        for (int q = 0; q < 16; q += 2) {
            float4 a = s4[q], b2 = s4[q + 1];
            *reinterpret_cast<uint4*>(dst + q * 4) =
                make_uint4(pk(a.x, a.y), pk(a.z, a.w), pk(b2.x, b2.y), pk(b2.z, b2.w));
        }
        {
            const float4* s1 = reinterpret_cast<const float4*>(k1w + (size_t)(p * H_ + h) * EF_);
            float4 a = s1[0], b2 = s1[1];
            *reinterpret_cast<uint4*>(dst + 64) =
                make_uint4(pk(a.x, a.y), pk(a.z, a.w), pk(b2.x, b2.y), pk(b2.z, b2.w));
        }
        {
            const float4* s2 = reinterpret_cast<const float4*>(k2w + (size_t)(p * H_ + h) * T_);
#pragma unroll
            for (int q = 0; q < 4; q += 2) {
                float4 a = s2[q], b2 = s2[q + 1];
                *reinterpret_cast<uint4*>(dst + 72 + q * 4) =
                    make_uint4(pk(a.x, a.y), pk(a.z, a.w), pk(b2.x, b2.y), pk(b2.z, b2.w));
            }
        }
        *reinterpret_cast<uint4*>(dst + 88) = make_uint4((u32)f2bf(k1b[p * H_ + h]), 0, 0, 0);
        *reinterpret_cast<uint4*>(dst + 96) = make_uint4(0, 0, 0, 0);
        *reinterpret_cast<uint4*>(dst + 104) = make_uint4(0, 0, 0, 0);
        *reinterpret_cast<uint4*>(dst + 112) = make_uint4(0, 0, 0, 0);
        *reinterpret_cast<uint4*>(dst + 120) = make_uint4(0, 0, 0, 0);
    } else if (blk < 100) {  // efb[p][e][8] from ef[p][e][9] cols 0..8
        int flat = (blk - 68) * 256 + t;  // p*1024+e
        const float* s = ef + (size_t)flat * (EF_ + 1);
        float v0 = s[0], v1 = s[1], v2 = s[2], v3 = s[3], v4 = s[4], v5 = s[5], v6 = s[6], v7 = s[7];
        *reinterpret_cast<uint4*>(efb + (size_t)flat * 8) =
            make_uint4(pk(v0, v1), pk(v2, v3), pk(v4, v5), pk(v6, v7));
    } else {  // k5wb[p][16][128], pre-swizzled, rows 8..15 zero
        int p = blk - 100;
        int row = t >> 4, col8 = (t & 15) * 8;
        uint4 o = make_uint4(0, 0, 0, 0);
        if (row < 8) {
            const float4* s = reinterpret_cast<const float4*>(k5w + (size_t)(p * W_ + row) * H_ + col8);
            float4 a = s[0], b2 = s[1];
            o = make_uint4(pk(a.x, a.y), pk(a.z, a.w), pk(b2.x, b2.y), pk(b2.z, b2.w));
        }
        int ch = (col8 >> 3) ^ (row & 7);
        *reinterpret_cast<uint4*>(k5wb + (size_t)p * 2048 + row * 128 + ch * 8) = o;
    }
}

// ---------------- K1 (MFMA): rx[b,p,e,f] = sum_m rinc[p,e,m] * x[b,nbr[p,m],f] ----------------
__global__ __launch_bounds__(256) void k_rx(const float* __restrict__ x,
                                            const u16* __restrict__ rincbf,
                                            const int* __restrict__ nbr,
                                            u16* __restrict__ rxbf) {
    const int et = blockIdx.x, p = blockIdx.y, b = blockIdx.z;
    const int t = threadIdx.x, lane = t & 63, wid = t >> 6;
    __shared__ __align__(16) u16 A_lds[128 * 64];
    __shared__ __align__(16) u16 BT_lds[64 * 64];
    f32x4 acc[2][4];
#pragma unroll
    for (int i = 0; i < 2; i++)
#pragma unroll
        for (int j = 0; j < 4; j++) acc[i][j] = 0.f;

    const int e0 = et * 128;
    for (int c = 0; c < 4; c++) {
        const int m0 = c * 64;
        __syncthreads();
        {
            int ee = t >> 1, seg = t & 1;
            const uint4* src = reinterpret_cast<const uint4*>(
                rincbf + ((size_t)(p * e_ + e0 + ee) * m_ + m0 + seg * 32));
#pragma unroll
            for (int q = 0; q < 4; q++) {
                uint4 v = src[q];
                int ch = (seg * 4 + q) ^ (ee & 7);
                *reinterpret_cast<uint4*>(A_lds + ee * 64 + ch * 8) = v;
            }
        }
        {
            int mm = t >> 2, fq = (t & 3) * 16;
            int row = nbr[p * m_ + m0 + mm];
            const float4* sx = reinterpret_cast<const float4*>(
                x + (size_t)(b * N_ + row) * F_ + fq);
#pragma unroll
            for (int q = 0; q < 4; q++) {
                float4 v = sx[q];
                int f0 = fq + q * 4;
                BT_lds[swzi(f0 + 0, mm)] = f2bf(v.x);
                BT_lds[swzi(f0 + 1, mm)] = f2bf(v.y);
                BT_lds[swzi(f0 + 2, mm)] = f2bf(v.z);
                BT_lds[swzi(f0 + 3, mm)] = f2bf(v.w);
            }
        }
        __syncthreads();
        const int wm0 = wid * 32, r15 = lane & 15, g4 = lane >> 4;
#pragma unroll
        for (int ks = 0; ks < 2; ks++) {
            int kb = ks * 32 + g4 * 8;
            bf16x8 af[2], bfr[4];
#pragma unroll
            for (int mf = 0; mf < 2; mf++) af[mf] = ldfrag(A_lds, wm0 + mf * 16 + r15, kb);
#pragma unroll
            for (int nf = 0; nf < 4; nf++) bfr[nf] = ldfrag(BT_lds, nf * 16 + r15, kb);
#pragma unroll
            for (int mf = 0; mf < 2; mf++)
#pragma unroll
                for (int nf = 0; nf < 4; nf++)
                    acc[mf][nf] = __builtin_amdgcn_mfma_f32_16x16x32_bf16(af[mf], bfr[nf], acc[mf][nf], 0, 0, 0);
        }
    }
    const int r15 = lane & 15, g4 = lane >> 4;
#pragma unroll
    for (int mf = 0; mf < 2; mf++)
#pragma unroll
        for (int nf = 0; nf < 4; nf++)
#pragma unroll
            for (int r = 0; r < 4; r++) {
                int erow = e0 + wid * 32 + mf * 16 + g4 * 4 + r;
                int f = nf * 16 + r15;
                rxbf[((size_t)(b * P_ + p) * e_ + erow) * F_ + f] = f2bf(acc[mf][nf][r]);
            }
}

// ---------------- K2: uT[b,p,h,n] (bf16) = sum_f k3_w[p,h,f] * x[b,nodes[p,n],f] ----------------
__global__ __launch_bounds__(256) void k_u(const float* __restrict__ x,
                                           const float* __restrict__ k3w,
                                           const int* __restrict__ nodes,
                                           u16* __restrict__ uT) {
    const int p = blockIdx.x, b = blockIdx.y;
    const int t = threadIdx.x;
    const int th = t & 15;
    const int tn = t >> 4;
    __shared__ float xg[128 * 64];
    __shared__ float kw[128 * 64];
    for (int idx = t; idx < 8192; idx += 256) {
        int r = idx >> 6, f = idx & 63;
        int row = nodes[p * n_ + r];
        xg[swz64(r, f)] = x[(size_t)(b * N_ + row) * F_ + f];
        kw[swz64(r, f)] = k3w[(size_t)(p * H_ + r) * F_ + f];
    }
    __syncthreads();
    float acc[8][8];
#pragma unroll
    for (int i = 0; i < 8; i++)
#pragma unroll
        for (int j = 0; j < 8; j++) acc[i][j] = 0.f;
#pragma unroll 2
    for (int k4 = 0; k4 < 16; k4++) {
        float4 xv[8];
#pragma unroll
        for (int i = 0; i < 8; i++) xv[i] = ld64(xg, tn * 8 + i, k4);
#pragma unroll
        for (int j = 0; j < 8; j++) {
            float4 kv = ld64(kw, th * 8 + j, k4);
#pragma unroll
            for (int i = 0; i < 8; i++) {
                acc[i][j] += xv[i].x * kv.x + xv[i].y * kv.y + xv[i].z * kv.z + xv[i].w * kv.w;
            }
        }
    }
    // write transposed bf16: uT[h][n]
#pragma unroll
    for (int j = 0; j < 8; j++) {
        uint4 o = make_uint4(pk(acc[0][j], acc[1][j]), pk(acc[2][j], acc[3][j]),
                             pk(acc[4][j], acc[5][j]), pk(acc[6][j], acc[7][j]));
        *reinterpret_cast<uint4*>(uT + ((size_t)(b * P_ + p) * H_ + th * 8 + j) * n_ + tn * 8) = o;
    }
}

// ---------------- K3 (MFMA): kernel[b,p,e,w] ----------------
__global__ __launch_bounds__(256) void k_kern(const u16* __restrict__ lincT,
                                              const u16* __restrict__ uT,
                                              const u16* __restrict__ rxbf,
                                              const u16* __restrict__ Bw,
                                              const u16* __restrict__ efb,
                                              const float* __restrict__ tin,
                                              const u16* __restrict__ k5wb,
                                              const float* __restrict__ k5b,
                                              float* __restrict__ kern) {
    const int et = blockIdx.x, p = blockIdx.y, b = blockIdx.z;
    const int t = threadIdx.x, lane = t & 63, wid = t >> 6;
    const int r15 = lane & 15, g4 = lane >> 4;
    const int wm = (wid >> 1) * 64, wn = (wid & 1) * 64;
    __shared__ __align__(16) u16 S[128 * 128 + 16 * 128];
    u16* A_lds = S;
    u16* B_lds = S + 8192;
    u16* k5l = S + 16384;

    {
        uint4 v = reinterpret_cast<const uint4*>(k5wb + (size_t)p * 2048)[t];
        reinterpret_cast<uint4*>(k5l)[t] = v;
    }
    uint4 tinlo, tinhi;
    {
        const float4* s = reinterpret_cast<const float4*>(tin + b * T_);
        float4 a = s[0], b2 = s[1], c2 = s[2], d2 = s[3];
        tinlo = make_uint4(pk(a.x, a.y), pk(a.z, a.w), pk(b2.x, b2.y), pk(b2.z, b2.w));
        tinhi = make_uint4(pk(c2.x, c2.y), pk(c2.z, c2.w), pk(d2.x, d2.y), pk(d2.z, d2.w));
    }

    f32x4 acc[4][4];
#pragma unroll
    for (int i = 0; i < 4; i++)
#pragma unroll
        for (int j = 0; j < 4; j++) acc[i][j] = 0.f;

    const int e0 = et * 128;
    const size_t pb_e = (size_t)(b * P_ + p) * e_;
    const int row = t >> 1, half = t & 1;

    for (int c = 0; c < 4; c++) {
        __syncthreads();
        if (c < 2) {
            const uint4* src = reinterpret_cast<const uint4*>(
                lincT + ((size_t)(p * e_) + e0 + row) * n_ + c * 64 + half * 32);
#pragma unroll
            for (int q = 0; q < 4; q++) {
                uint4 v = src[q];
                int ch = (half * 4 + q) ^ (row & 7);
                *reinterpret_cast<uint4*>(A_lds + row * 64 + ch * 8) = v;
            }
        } else if (c == 2) {
            const uint4* src = reinterpret_cast<const uint4*>(
                rxbf + (pb_e + e0 + row) * F_ + half * 32);
#pragma unroll
            for (int q = 0; q < 4; q++) {
                uint4 v = src[q];
                int ch = (half * 4 + q) ^ (row & 7);
                *reinterpret_cast<uint4*>(A_lds + row * 64 + ch * 8) = v;
            }
        } else {
            uint4 w[4];
            if (half == 0) {
                w[0] = *reinterpret_cast<const uint4*>(efb + ((size_t)(p * e_) + e0 + row) * 8);
                w[1] = tinlo;
                w[2] = tinhi;
                w[3] = make_uint4(0x00003F80u, 0, 0, 0);
            } else {
                w[0] = w[1] = w[2] = w[3] = make_uint4(0, 0, 0, 0);
            }
#pragma unroll
            for (int q = 0; q < 4; q++) {
                int ch = (half * 4 + q) ^ (row & 7);
                *reinterpret_cast<uint4*>(A_lds + row * 64 + ch * 8) = w[q];
            }
        }
        {
            const uint4* src;
            if (c < 2)
                src = reinterpret_cast<const uint4*>(
                    uT + ((size_t)(b * P_ + p) * H_ + row) * n_ + c * 64 + half * 32);
            else
                src = reinterpret_cast<const uint4*>(
                    Bw + (size_t)(p * H_ + row) * 128 + (c - 2) * 64 + half * 32);
#pragma unroll
            for (int q = 0; q < 4; q++) {
                uint4 v = src[q];
                int ch = (half * 4 + q) ^ (row & 7);
                *reinterpret_cast<uint4*>(B_lds + row * 64 + ch * 8) = v;
            }
        }
        __syncthreads();
#pragma unroll
        for (int ks = 0; ks < 2; ks++) {
            int kb = ks * 32 + g4 * 8;
            bf16x8 af[4], bfr[4];
#pragma unroll
            for (int mf = 0; mf < 4; mf++) af[mf] = ldfrag(A_lds, wm + mf * 16 + r15, kb);
#pragma unroll
            for (int nf = 0; nf < 4; nf++) bfr[nf] = ldfrag(B_lds, wn + nf * 16 + r15, kb);
#pragma unroll
            for (int mf = 0; mf < 4; mf++)
#pragma unroll
                for (int nf = 0; nf < 4; nf++)
                    acc[mf][nf] = __builtin_amdgcn_mfma_f32_16x16x32_bf16(af[mf], bfr[nf], acc[mf][nf], 0, 0, 0);
        }
    }
    __syncthreads();
    u16* Kl = S;
#pragma unroll
    for (int mf = 0; mf < 4; mf++)
#pragma unroll
        for (int nf = 0; nf < 4; nf++)
#pragma unroll
            for (int r = 0; r < 4; r++) {
                int er = wm + mf * 16 + g4 * 4 + r;
                int hc = wn + nf * 16 + r15;
                Kl[swzi128(er, hc)] = f2bf(leakyf(acc[mf][nf][r], 0.02f));
            }
    __syncthreads();
    f32x4 acc2[2];
    acc2[0] = 0.f;
    acc2[1] = 0.f;
#pragma unroll
    for (int ks = 0; ks < 4; ks++) {
        int kb = ks * 32 + g4 * 8;
        bf16x8 bf5 = ldfrag128(k5l, r15, kb);
#pragma unroll
        for (int mf2 = 0; mf2 < 2; mf2++) {
            bf16x8 af = ldfrag128(Kl, wid * 32 + mf2 * 16 + r15, kb);
            acc2[mf2] = __builtin_amdgcn_mfma_f32_16x16x32_bf16(af, bf5, acc2[mf2], 0, 0, 0);
        }
    }
    if (r15 < 8) {
        float kb5 = k5b[p * W_ + r15];
#pragma unroll
        for (int mf2 = 0; mf2 < 2; mf2++)
#pragma unroll
            for (int r = 0; r < 4; r++) {
                int er = e0 + wid * 32 + mf2 * 16 + g4 * 4 + r;
                kern[(pb_e + er) * W_ + r15] = fmaxf(acc2[mf2][r] + kb5, 0.f);
            }
    }
}

// ---------------- K4 (MFMA): QT[b,p,g,e] = sum_{w,f} (kern[e,w]*rx[e,f]) * gcw[g,w*F+f] ----------
// Round-8 structure, 512 threads: per-w staging VALU per thread halved; 8 waves (2m x 4n),
// per-wave 64e x 32g (acc[4][2]).
__global__ __launch_bounds__(512) void k_q(const u16* __restrict__ rxbf,
                                           const float* __restrict__ kernb,
                                           const u16* __restrict__ gcwbf,
                                           u16* __restrict__ QTbf) {
    const int et = blockIdx.x, p = blockIdx.y, b = blockIdx.z;
    const int t = threadIdx.x, lane = t & 63, wid = t >> 6;
    __shared__ __align__(16) u16 A_lds[128 * 64];
    __shared__ __align__(16) u16 BT_lds[128 * 64];
    f32x4 acc[4][2];
#pragma unroll
    for (int i = 0; i < 4; i++)
#pragma unroll
        for (int j = 0; j < 2; j++) acc[i][j] = 0.f;

    const int e0 = et * 128;
    const size_t pb_e = (size_t)(b * P_ + p) * e_;
    const int wm = (wid >> 2) * 64, wn = (wid & 3) * 32;
    const int r15 = lane & 15, g4 = lane >> 4;
    const int ee = t >> 2, seg = t & 3;

    for (int w = 0; w < 8; w++) {
        __syncthreads();
        {   // A: bf16(kern[e,w] * rx[e,f]) — each thread 2 uint4 (16 values)
            float ksc = kernb[(pb_e + e0 + ee) * W_ + w];
            const uint4* src = reinterpret_cast<const uint4*>(rxbf + (pb_e + e0 + ee) * F_ + seg * 16);
#pragma unroll
            for (int q = 0; q < 2; q++) {
                uint4 v = src[q];
                u32 vv[4] = {v.x, v.y, v.z, v.w};
                u32 ov[4];
#pragma unroll
                for (int q2 = 0; q2 < 4; q2++) {
                    float f0 = bf2f((u16)(vv[q2] & 0xFFFF)) * ksc;
                    float f1 = bf2f((u16)(vv[q2] >> 16)) * ksc;
                    ov[q2] = (u32)f2bf(f0) | ((u32)f2bf(f1) << 16);
                }
                int ch = (seg * 2 + q) ^ (ee & 7);
                *reinterpret_cast<uint4*>(A_lds + ee * 64 + ch * 8) =
                    make_uint4(ov[0], ov[1], ov[2], ov[3]);
            }
        }
        {   // B: copy gcwbf rows [g][w*64 .. +64] — each thread 2 uint4
            const uint4* src = reinterpret_cast<const uint4*>(
                gcwbf + (size_t)(p * G_ + ee) * 512 + w * 64 + seg * 16);
#pragma unroll
            for (int q = 0; q < 2; q++) {
                uint4 v = src[q];
                int ch = (seg * 2 + q) ^ (ee & 7);
                *reinterpret_cast<uint4*>(BT_lds + ee * 64 + ch * 8) = v;
            }
        }
        __syncthreads();
#pragma unroll
        for (int ks = 0; ks < 2; ks++) {
            int kb = ks * 32 + g4 * 8;
            bf16x8 af[4], bfr[2];
#pragma unroll
            for (int mf = 0; mf < 4; mf++) af[mf] = ldfrag(A_lds, wm + mf * 16 + r15, kb);
#pragma unroll
            for (int nf = 0; nf < 2; nf++) bfr[nf] = ldfrag(BT_lds, wn + nf * 16 + r15, kb);
#pragma unroll
            for (int mf = 0; mf < 4; mf++)
#pragma unroll
                for (int nf = 0; nf < 2; nf++)
                    acc[mf][nf] = __builtin_amdgcn_mfma_f32_16x16x32_bf16(af[mf], bfr[nf], acc[mf][nf], 0, 0, 0);
        }
    }
    // write QT[b,p,g,e]: per lane 4 e-contiguous bf16 -> ushort4 store
#pragma unroll
    for (int mf = 0; mf < 4; mf++)
#pragma unroll
        for (int nf = 0; nf < 2; nf++) {
            int g = wn + nf * 16 + r15;
            int er = e0 + wm + mf * 16 + g4 * 4;
            ushort4 o = make_ushort4(f2bf(acc[mf][nf][0]), f2bf(acc[mf][nf][1]),
                                     f2bf(acc[mf][nf][2]), f2bf(acc[mf][nf][3]));
            *reinterpret_cast<ushort4*>(QTbf + ((size_t)(b * P_ + p) * G_ + g) * e_ + er) = o;
        }
}

// ---------------- K5 (MFMA): y2[b,p,n,g] = relu(sum_e linc[n,e]*QT[g,e] + gcb[g]) ----------------
__global__ __launch_bounds__(256) void k_y2(const u16* __restrict__ lincbf,
                                            const u16* __restrict__ QTbf,
                                            const float* __restrict__ gcb,
                                            float* __restrict__ y2) {
    const int p = blockIdx.x, b = blockIdx.y;
    const int t = threadIdx.x, lane = t & 63, wid = t >> 6;
    __shared__ __align__(16) u16 A_lds[128 * 64];
    __shared__ __align__(16) u16 BT_lds[128 * 64];
    f32x4 acc[4][4];
#pragma unroll
    for (int i = 0; i < 4; i++)
#pragma unroll
        for (int j = 0; j < 4; j++) acc[i][j] = 0.f;

    const size_t pb_g = (size_t)(b * P_ + p) * G_;
    const int wm = (wid >> 1) * 64, wn = (wid & 1) * 64;
    const int r15 = lane & 15, g4 = lane >> 4;

    for (int c = 0; c < 16; c++) {
        const int e0 = c * 64;
        __syncthreads();
        {
            int nn = t >> 1, seg = t & 1;
            const uint4* src = reinterpret_cast<const uint4*>(
                lincbf + (size_t)(p * n_ + nn) * e_ + e0 + seg * 32);
#pragma unroll
            for (int q = 0; q < 4; q++) {
                uint4 v = src[q];
                int ch = (seg * 4 + q) ^ (nn & 7);
                *reinterpret_cast<uint4*>(A_lds + nn * 64 + ch * 8) = v;
            }
        }
        {
            int gg = t >> 1, seg = t & 1;
            const uint4* src = reinterpret_cast<const uint4*>(
                QTbf + (pb_g + gg) * e_ + e0 + seg * 32);
#pragma unroll
            for (int q = 0; q < 4; q++) {
                uint4 v = src[q];
                int ch = (seg * 4 + q) ^ (gg & 7);
                *reinterpret_cast<uint4*>(BT_lds + gg * 64 + ch * 8) = v;
            }
        }
        __syncthreads();
#pragma unroll
        for (int ks = 0; ks < 2; ks++) {
            int kb = ks * 32 + g4 * 8;
            bf16x8 af[4], bfr[4];
#pragma unroll
            for (int mf = 0; mf < 4; mf++) af[mf] = ldfrag(A_lds, wm + mf * 16 + r15, kb);
#pragma unroll
            for (int nf = 0; nf < 4; nf++) bfr[nf] = ldfrag(BT_lds, wn + nf * 16 + r15, kb);
#pragma unroll
            for (int mf = 0; mf < 4; mf++)
#pragma unroll
                for (int nf = 0; nf < 4; nf++)
                    acc[mf][nf] = __builtin_amdgcn_mfma_f32_16x16x32_bf16(af[mf], bfr[nf], acc[mf][nf], 0, 0, 0);
        }
    }
#pragma unroll
    for (int mf = 0; mf < 4; mf++)
#pragma unroll
        for (int nf = 0; nf < 4; nf++) {
            int g = wn + nf * 16 + r15;
            float gb = gcb[p * G_ + g];
#pragma unroll
            for (int r = 0; r < 4; r++) {
                int nrow = wm + mf * 16 + g4 * 4 + r;
                y2[((size_t)(b * P_ + p) * n_ + nrow) * G_ + g] = fmaxf(acc[mf][nf][r] + gb, 0.f);
            }
        }
}

// ---------------- K6 (MFMA): hpart[ks,p,b,r] = sum_{k in slice} r0_w[p,r,k]*y2flat[b,p,k] ----
__global__ __launch_bounds__(256) void k_h1(const float* __restrict__ r0w,
                                            const float* __restrict__ y2,
                                            float* __restrict__ hpart) {
    const int ks = blockIdx.x;   // 0..31 (512 k each)
    const int rt = blockIdx.y;   // 0..3  (64 rows each)
    const int p  = blockIdx.z;
    const int t = threadIdx.x, lane = t & 63, wid = t >> 6;
    const int r15 = lane & 15, g4 = lane >> 4;
    __shared__ __align__(16) u16 A_lds[64 * 128];  // [r][k] swizzled
    __shared__ __align__(16) u16 B_lds[32 * 128];  // [b][k] swizzled
    const int kc = ks * 512;
    const int row0 = rt * 64;

    f32x4 acc[2];
    acc[0] = 0.f;
    acc[1] = 0.f;

    const int sar = t >> 2, sas = t & 3;  // A: row (0..63), 32-float segment
    const int sbb = t >> 3, sbs = t & 7;  // B: b-row (0..31), 16-float segment

    for (int it = 0; it < 4; it++) {
        __syncthreads();
        {   // A: r0w rows (f32 -> bf16), 32 contiguous floats per thread
            const float4* src = reinterpret_cast<const float4*>(
                r0w + ((size_t)(p * R_) + row0 + sar) * 16384 + kc + it * 128 + sas * 32);
#pragma unroll
            for (int q = 0; q < 4; q++) {
                float4 a = src[q * 2], b2 = src[q * 2 + 1];
                uint4 o = make_uint4(pk(a.x, a.y), pk(a.z, a.w), pk(b2.x, b2.y), pk(b2.z, b2.w));
                int ch = (sas * 4 + q) ^ (sar & 7);
                *reinterpret_cast<uint4*>(A_lds + sar * 128 + ch * 8) = o;
            }
        }
        {   // B: y2 rows (f32 -> bf16), 16 contiguous floats per thread
            const float4* src = reinterpret_cast<const float4*>(
                y2 + (size_t)(sbb * P_ + p) * 16384 + kc + it * 128 + sbs * 16);
            float4 a = src[0], b2 = src[1], c2 = src[2], d2 = src[3];
            uint4 o0 = make_uint4(pk(a.x, a.y), pk(a.z, a.w), pk(b2.x, b2.y), pk(b2.z, b2.w));
            uint4 o1 = make_uint4(pk(c2.x, c2.y), pk(c2.z, c2.w), pk(d2.x, d2.y), pk(d2.z, d2.w));
            int ch0 = (sbs * 2) ^ (sbb & 7);
            int ch1 = (sbs * 2 + 1) ^ (sbb & 7);
            *reinterpret_cast<uint4*>(B_lds + sbb * 128 + ch0 * 8) = o0;
            *reinterpret_cast<uint4*>(B_lds + sbb * 128 + ch1 * 8) = o1;
        }
        __syncthreads();
#pragma unroll
        for (int ksl = 0; ksl < 4; ksl++) {
            int kb = ksl * 32 + g4 * 8;
            bf16x8 af = ldfrag128(A_lds, wid * 16 + r15, kb);
#pragma unroll
            for (int nf = 0; nf < 2; nf++) {
                bf16x8 bfr = ldfrag128(B_lds, nf * 16 + r15, kb);
                acc[nf] = __builtin_amdgcn_mfma_f32_16x16x32_bf16(af, bfr, acc[nf], 0, 0, 0);
            }
        }
    }
#pragma unroll
    for (int nf = 0; nf < 2; nf++) {
        int b = nf * 16 + r15;
        int r = row0 + wid * 16 + g4 * 4;
        float4 v = make_float4(acc[nf][0], acc[nf][1], acc[nf][2], acc[nf][3]);
        *reinterpret_cast<float4*>(hpart + (((size_t)(ks * P_ + p) * 32 + b) * 256 + r)) = v;
    }
}

// ---------------- K7: h -> leaky -> w -> res ----------------
__global__ __launch_bounds__(128) void k_wres(const float* __restrict__ hpart,
                                              const float* __restrict__ r1w,
                                              const float* __restrict__ r1b,
                                              const float* __restrict__ r2w,
                                              const float* __restrict__ cap,
                                              const float* __restrict__ tin,
                                              const float* __restrict__ r3w,
                                              const float* __restrict__ r3b,
                                              const float* __restrict__ y2,
                                              float* __restrict__ res) {
    const int p = blockIdx.x, b = blockIdx.y;
    const int t = threadIdx.x;
    __shared__ float lh[256];
    __shared__ float wl[128];
    for (int rr = t; rr < 256; rr += 128) {
        float s = 0.f;
        for (int ks = 0; ks < 32; ks++)
            s += hpart[(((size_t)(ks * P_ + p) * 32 + b) * 256) + rr];
        for (int tt = 0; tt < T_; tt++) s += r1w[(size_t)(p * R_ + rr) * T_ + tt] * tin[b * T_ + tt];
        s += r1b[p * R_ + rr];
        for (int nn = 0; nn < n_; nn++) s += r2w[(size_t)(p * R_ + rr) * n_ + nn] * cap[p * n_ + nn];
        lh[rr] = leakyf(s, 0.01f);
    }
    __syncthreads();
    {
        const int nn = t;
        float accw = r3b[p * n_ + nn];
        const float* r3p = r3w + (size_t)(p * n_ + nn) * R_;
        for (int r = 0; r < 256; r += 4) {
            float4 rv = *reinterpret_cast<const float4*>(r3p + r);
            accw += rv.x * lh[r] + rv.y * lh[r + 1] + rv.z * lh[r + 2] + rv.w * lh[r + 3];
        }
        wl[nn] = fmaxf(accw, 0.f);
    }
    __syncthreads();
    {
        const int g = t;
        float a = 0.f;
        for (int nn = 0; nn < n_; nn++) a += wl[nn] * y2[((size_t)(b * P_ + p) * n_ + nn) * G_ + g];
        res[(b * P_ + p) * G_ + g] = a;
    }
}

// ---------------- K8: out[b,l] ----------------
__global__ __launch_bounds__(128) void k_out(const float* __restrict__ convw,
                                             const float* __restrict__ convb,
                                             const float* __restrict__ res,
                                             float* __restrict__ out) {
    const int b = blockIdx.x;
    const int t = threadIdx.x;
    __shared__ float rl[1024];
    for (int idx = t; idx < 1024; idx += 128) rl[idx] = res[b * 1024 + idx];
    __syncthreads();
    float a = convb[t];
    const float* cw = convw + (size_t)t * 1024;
    for (int gp = 0; gp < 1024; gp += 4) {
        float4 v = *reinterpret_cast<const float4*>(cw + gp);
        a += v.x * rl[((gp + 0) & 7) * 128 + ((gp + 0) >> 3)];
        a += v.y * rl[((gp + 1) & 7) * 128 + ((gp + 1) >> 3)];
        a += v.z * rl[((gp + 2) & 7) * 128 + ((gp + 2) >> 3)];
        a += v.w * rl[((gp + 3) & 7) * 128 + ((gp + 3) >> 3)];
    }
    out[b * L2_ + t] = leakyf(a, 0.02f);
}

extern "C" void kernel_launch(void* const* d_in, const int* in_sizes, int n_in,
                              void* d_out, int out_size, void* d_ws, size_t ws_size,
                              hipStream_t stream) {
    const float* x    = (const float*)d_in[0];
    const float* tin  = (const float*)d_in[1];
    const float* ef   = (const float*)d_in[2];
    const float* linc = (const float*)d_in[3];
    const float* rinc = (const float*)d_in[4];
    const float* cap  = (const float*)d_in[5];
    const float* k1w  = (const float*)d_in[6];
    const float* k1b  = (const float*)d_in[7];
    const float* k2w  = (const float*)d_in[8];
    const float* k3w  = (const float*)d_in[9];
    const float* k4w  = (const float*)d_in[10];
    const float* k5w  = (const float*)d_in[11];
    const float* k5b  = (const float*)d_in[12];
    const float* gcw  = (const float*)d_in[13];
    const float* gcb  = (const float*)d_in[14];
    const float* r0w  = (const float*)d_in[15];
    const float* r1w  = (const float*)d_in[16];
    const float* r1b  = (const float*)d_in[17];
    const float* r2w  = (const float*)d_in[18];
    const float* r3w  = (const float*)d_in[19];
    const float* r3b  = (const float*)d_in[20];
    const float* convw = (const float*)d_in[21];
    const float* convb = (const float*)d_in[22];
    const int* nodes  = (const int*)d_in[23];
    const int* nbr    = (const int*)d_in[24];
    float* out = (float*)d_out;

    float* ws = (float*)d_ws;
    u16*   rxbf   = (u16*)ws;                  // [0, 8388608) f-slots
    u16*   uTbf   = (u16*)(ws + 8388608);      // [8388608, 10485760)
    float* kernb  = ws + 10485760;             // [10485760, 12582912)
    u16*   QTbf   = (u16*)(ws + 12582912);     // [12582912, 29360128)
    float* y2b    = ws + 29360128;             // [29360128, 33554432)
    u16*   lincbf = (u16*)(ws + 33554432);     // 524288 slots
    u16*   lincT  = (u16*)(ws + 34078720);     // 524288
    u16*   rincbf = (u16*)(ws + 34603008);     // 1048576
    u16*   gcwbf  = (u16*)(ws + 35651584);     // 262144
    u16*   Bwbf   = (u16*)(ws + 35913728);     // 65536
    u16*   efbf   = (u16*)(ws + 35979264);     // 32768
    u16*   k5wbf  = (u16*)(ws + 36012032);     // 8192
    float* hpart  = ws;                        // 2,097,152 floats: aliases rx region (dead after k_q)
    float* resb   = ws + 10485760;             // aliases kernb (dead after k_q)

    k_prep <<<3584, 256, 0, stream>>>(linc, rinc, gcw, lincbf, rincbf, gcwbf);
    k_prep2<<<108, 256, 0, stream>>>(linc, k4w, k1w, k2w, k1b, ef, k5w, lincT, Bwbf, efbf, k5wbf);
    k_rx  <<<dim3(8, P_, B_), 256, 0, stream>>>(x, rincbf, nbr, rxbf);
    k_u   <<<dim3(P_, B_),    256, 0, stream>>>(x, k3w, nodes, uTbf);
    k_kern<<<dim3(8, P_, B_), 256, 0, stream>>>(lincT, uTbf, rxbf, Bwbf, efbf, tin, k5wbf, k5b, kernb);
    k_q   <<<dim3(8, P_, B_), 512, 0, stream>>>(rxbf, kernb, gcwbf, QTbf);
    k_y2  <<<dim3(P_, B_),    256, 0, stream>>>(lincbf, QTbf, gcb, y2b);
    k_h1  <<<dim3(32, 4, P_), 256, 0, stream>>>(r0w, y2b, hpart);
    k_wres<<<dim3(P_, B_),    128, 0, stream>>>(hpart, r1w, r1b, r2w, cap, tin, r3w, r3b, y2b, resb);
    k_out <<<B_, 128, 0, stream>>>(convw, convb, resb, out);
}